// Round 9
// baseline (5211.742 us; speedup 1.0000x reference)
//
#include <hip/hip_runtime.h>
#include <math.h>

#define TT 36
#define NP 160
#define KDIM 641
#define PP 512
#define KPAD 704          // transposed-x row stride
#define NU 321            // pair-units: u=0 const col; 1..160 cos; 161..320 sin
#define NSLOT 384         // padded unit slots (321..383 stay zero)
#define BT 512            // 8 waves
#define LAM 0.1f
#define EPSW 0.01f
#define NITER 200
#define NPOW 160

// ---------------- dictionary ----------------
__global__ void k_build_dic(const float* __restrict__ rr, const float* __restrict__ th,
                            float* __restrict__ D, float* __restrict__ outD) {
  int idx = blockIdx.x * blockDim.x + threadIdx.x;
  if (idx >= TT * KDIM) return;
  int t = idx / KDIM, k = idx % KDIM;
  float v;
  if (k == 0) {
    v = 1.0f;
  } else {
    int g = (k - 1) / NP;     // 0:p*cos 1:m*cos 2:p*sin 3:m*sin
    int p = (k - 1) % NP;
    float ft = (float)t;
    float pw = powf(rr[p], ft);
    if ((g == 1 || g == 3) && (t & 1)) pw = -pw;
    float ang = ft * th[p];
    v = pw * ((g < 2) ? cosf(ang) : sinf(ang));
  }
  D[idx] = v;
  outD[idx] = v;
}

// ---------------- G = D D^T (36x36) ----------------
__global__ void k_G(const float* __restrict__ D, float* __restrict__ G) {
  int idx = blockIdx.x * blockDim.x + threadIdx.x;
  if (idx >= TT * TT) return;
  int i = idx / TT, j = idx % TT;
  float s = 0.0f;
  for (int k = 0; k < KDIM; ++k) s = fmaf(D[i * TT == 0 ? 0 : i * KDIM + k], D[j * KDIM + k], s);
  // (expression above is always D[i*KDIM+k]; written plainly below)
  s = 0.0f;
  for (int k = 0; k < KDIM; ++k) s = fmaf(D[i * KDIM + k], D[j * KDIM + k], s);
  G[idx] = s;
}

// ---------------- power iteration on 36x36 (one wave): L = ||DtD||_2; mu table ----------------
__global__ void k_power(const float* __restrict__ G, float* __restrict__ Lb,
                        float* __restrict__ mug) {
  int lane = threadIdx.x;   // blockDim = 64
  float g[TT];
#pragma unroll
  for (int j = 0; j < TT; ++j) g[j] = (lane < TT) ? G[lane * TT + j] : 0.0f;
  float v = (lane < TT) ? 1.0f : 0.0f;
  for (int it = 0; it < NPOW; ++it) {
    float u = 0.0f;
#pragma unroll
    for (int j = 0; j < TT; ++j) u = fmaf(g[j], __shfl(v, j, 64), u);
    float s = u * u;
#pragma unroll
    for (int o = 32; o >= 1; o >>= 1) s += __shfl_xor(s, o, 64);
    v = u * rsqrtf(s);
  }
  float u = 0.0f;
#pragma unroll
  for (int j = 0; j < TT; ++j) u = fmaf(g[j], __shfl(v, j, 64), u);
  float num = v * u, den = v * v;
#pragma unroll
  for (int o = 32; o >= 1; o >>= 1) {
    num += __shfl_xor(num, o, 64);
    den += __shfl_xor(den, o, 64);
  }
  if (lane == 0) {
    float L = num / den;   // Rayleigh quotient = lambda_max
    Lb[0] = L;
    Lb[1] = 1.0f / L;
    Lb[3] = 0.0f;          // reset norm accumulator (graph-replay safe)
    float t = 1.0f;
    for (int i = 0; i < NITER; ++i) {
      float tn = 0.5f * (1.0f + sqrtf(1.0f + 4.0f * t * t));
      mug[i] = (t - 1.0f) / tn;
      t = tn;
    }
  }
}

// ---- DPP wave-64 sum; total valid in lanes 48..63 ----
template <int C>
__device__ __forceinline__ float dppadd(float v) {
  int t = __builtin_amdgcn_update_dpp(0, __float_as_int(v), C, 0xf, 0xf, true);
  return v + __int_as_float(t);
}
__device__ __forceinline__ float wave_sum63(float v) {
  v = dppadd<0xB1>(v);    // quad_perm [1,0,3,2]
  v = dppadd<0x4E>(v);    // quad_perm [2,3,0,1]
  v = dppadd<0x141>(v);   // row_half_mirror
  v = dppadd<0x140>(v);   // row_mirror
  v = dppadd<0x142>(v);   // row_bcast15
  v = dppadd<0x143>(v);   // row_bcast31
  return v;               // lanes 48..63 hold the total
}

// plus-group column index of pair-unit u (u < NU)
__device__ __forceinline__ int colmap(int u) {
  return (u == 0) ? 0 : ((u < 161) ? u : u + 160);
}

// ---------------- persistent per-round FISTA: one column per block, 8 waves ----------------
__global__ __attribute__((amdgpu_flat_work_group_size(BT, BT), amdgpu_waves_per_eu(4, 4)))
void k_round(
    const float* __restrict__ Dg, const float* __restrict__ X,
    float* __restrict__ Lb, const float* __restrict__ mug,
    const float* __restrict__ xprev, float* __restrict__ xout,
    int first, int last) {
  __shared__ __align__(16) float2 ylds2[NSLOT];   // slot u = (yP_u, yM_u)
  __shared__ float sEl[NSLOT];                    // even-row partial sums
  __shared__ float sOl[NSLOT];                    // odd-row partial sums
  __shared__ float muLDS[NITER];
  __shared__ float rn[8];

  const int tid  = threadIdx.x;
  const int lane = tid & 63;
  const int w    = tid >> 6;          // wave 0..7
  const int nr   = (w < 4) ? 5 : 4;   // rows owned: t = w + 8i, i < nr
  const bool odd = (w & 1);           // row parity uniform per wave
  const float sgn = odd ? -1.0f : 1.0f;
  const int p    = blockIdx.x;        // column

  const float Linv = Lb[1];
  const float sqL  = sqrtf(Linv);
  const float lamL = LAM * Linv;

  // ---- pair-unit ownership: one per thread (tid < NU)
  const int u = tid;
  const bool act = (u < NU);
  const int kP = colmap(act ? u : 0);
  const int kM = (u == 0 || !act) ? 0 : kP + 160;

  // ---- Dq[i][j] = sqrt(Linv) * D[w+8i][colmap(lane+64j)]; zero pad
  float Dq[5][6];
#pragma unroll
  for (int i = 0; i < 5; ++i)
#pragma unroll
    for (int j = 0; j < 6; ++j) {
      const int ua = lane + 64 * j;
      Dq[i][j] = (i < nr && ua < NU) ? Dg[(w + 8 * i) * KDIM + colmap(ua)] * sqL : 0.0f;
    }

  // ---- c0 = Linv*(D^T x_col) via even/odd split (direct global reads, one-time)
  float cmP, cpP, cmM, cpM;
  {
    float sE0 = 0.f, sO0 = 0.f;
#pragma unroll 6
    for (int t = 0; t < TT; ++t) {
      const float dv = act ? Dg[t * KDIM + kP] : 0.0f;
      const float xv = X[t * PP + p];       // block-uniform: scalar load
      if (t & 1) sO0 = fmaf(dv, xv, sO0);
      else       sE0 = fmaf(dv, xv, sE0);
    }
    const float c0P = (sE0 + sO0) * Linv, c0M = (sE0 - sO0) * Linv;
    float wlP = lamL, wlM = lamL;
    if (!first) {
      const float nl = lamL * Lb[2];        // lam*Linv/||wr||
      wlP = nl / (fabsf(xprev[p * KPAD + kP]) + EPSW);
      wlM = nl / (fabsf(xprev[p * KPAD + ((u > 0) ? kM : kP)]) + EPSW);
    }
    cmP = c0P - wlP; cpP = c0P + wlP;
    cmM = c0M - wlM; cpM = c0M + wlM;
  }

  // ---- init LDS: y pairs, partial arrays, mu table
  if (tid < NSLOT) {
    ylds2[tid] = make_float2(0.f, 0.f);
    sEl[tid] = 0.f;
    sOl[tid] = 0.f;
  }
  if (tid < NITER) muLDS[tid] = mug[tid];

  float xP = 0.f, xM = 0.f, yP = 0.f, yM = 0.f;

  __syncthreads();

  float* const sbase = odd ? sOl : sEl;     // this wave's parity bucket

  for (int it = 0; it < NITER; ++it) {
    // ===== phase 1: z_rows = sqrtL * (D @ y), pole-paired =====
    float acc[5] = {0.f, 0.f, 0.f, 0.f, 0.f};
#pragma unroll
    for (int j = 0; j < 6; ++j) {
      const float2 yv = ylds2[lane + 64 * j];   // ds_read_b64, conflict-free
      const float op = fmaf(sgn, yv.y, yv.x);   // yP ± yM, parity wave-uniform
#pragma unroll
      for (int i = 0; i < 5; ++i) acc[i] = fmaf(Dq[i][j], op, acc[i]);
    }
    // reduce; z in SGPRs (uniform) via readlane
    float z[5];
#pragma unroll
    for (int i = 0; i < 5; ++i) {
      const float r = wave_sum63(acc[i]);
      z[i] = __int_as_float(__builtin_amdgcn_readlane(__float_as_int(r), 63));
    }
    // ===== phase-2 partials: pw[j] = sum_i Dq[i][j]*z[i]; accumulate by parity =====
#pragma unroll
    for (int j = 0; j < 6; ++j) {
      float pw = Dq[0][j] * z[0];
      pw = fmaf(Dq[1][j], z[1], pw);
      pw = fmaf(Dq[2][j], z[2], pw);
      pw = fmaf(Dq[3][j], z[3], pw);
      pw = fmaf(Dq[4][j], z[4], pw);
      atomicAdd(&sbase[lane + 64 * j], pw);     // ds_add_f32, stride-4: conflict-free
    }
    __syncthreads();

    // ===== owner: reconstruct both pair rows, shrink, momentum =====
    const float mu = muLDS[it];
    if (act) {
      const float se = sEl[u], so = sOl[u];
      sEl[u] = 0.f; sOl[u] = 0.f;               // re-zero for next iter
      const float sP = se + so, sM = se - so;   // = Linv*(DtD y) rows kP,kM
      float uu, xn;
      uu = yP - sP; xn = fmaxf(0.f, uu + cmP) + fminf(0.f, uu + cpP);
      yP = fmaf(mu, xn - xP, xn); xP = xn;
      uu = yM - sM; xn = fmaxf(0.f, uu + cmM) + fminf(0.f, uu + cpM);
      yM = fmaf(mu, xn - xM, xn); xM = xn;
      ylds2[u] = make_float2(yP, (u > 0) ? yM : 0.0f);
    }
    __syncthreads();
  }

  // ---- emit x
  if (act) {
    if (last) {
      xout[kP * PP + p] = xP;
      if (u > 0) xout[kM * PP + p] = xM;
    } else {
      xout[p * KPAD + kP] = xP;             // transposed for next round's reads
      if (u > 0) xout[p * KPAD + kM] = xM;
    }
  }

  // ---- fused reweight-norm accumulation: sum of wr^2 over this column
  if (!last) {
    float s = 0.0f;
    if (act) {
      const float rP = 1.0f / (fabsf(xP) + EPSW);
      s = rP * rP;
      if (u > 0) { const float rM = 1.0f / (fabsf(xM) + EPSW); s += rM * rM; }
    }
    s = wave_sum63(s);
    if (lane == 63) rn[w] = s;
    __syncthreads();
    if (tid == 0) {
      float tot = 0.f;
#pragma unroll
      for (int i = 0; i < 8; ++i) tot += rn[i];
      atomicAdd(&Lb[3], tot);
    }
  }
}

// ---------------- finalize norm: Lb[2] = 1/||wr||, reset accumulator ----------------
__global__ void k_norm(float* __restrict__ Lb) {
  if (threadIdx.x == 0) {
    Lb[2] = 1.0f / sqrtf(Lb[3]);
    Lb[3] = 0.0f;
  }
}

// ---------------- host ----------------
extern "C" void kernel_launch(void* const* d_in, const int* in_sizes, int n_in,
                              void* d_out, int out_size, void* d_ws, size_t ws_size,
                              hipStream_t stream) {
  const float* x  = (const float*)d_in[0];
  const float* rr = (const float*)d_in[1];
  const float* th = (const float*)d_in[2];
  float* out = (float*)d_out;
  float* ws  = (float*)d_ws;

  size_t off = 0;
  auto alloc = [&](size_t n) {
    float* p = ws + off;
    off += (n + 63) & ~(size_t)63;
    return p;
  };
  float* D    = alloc((size_t)TT * KDIM);
  float* G    = alloc(TT * TT);
  float* Lb   = alloc(16);
  float* mug  = alloc(NITER);
  float* xa   = alloc((size_t)PP * KPAD);   // transposed intermediate x
  if (off * sizeof(float) > ws_size) return;

  k_build_dic<<<(TT * KDIM + 255) / 256, 256, 0, stream>>>(rr, th, D, out + (size_t)KDIM * PP);
  k_G<<<(TT * TT + 255) / 256, 256, 0, stream>>>(D, G);
  k_power<<<1, 64, 0, stream>>>(G, Lb, mug);

  for (int r = 0; r < 3; ++r) {
    const int first = (r == 0), last = (r == 2);
    float* xo = last ? out : xa;
    k_round<<<PP, BT, 0, stream>>>(D, x, Lb, mug, xa, xo, first, last);
    if (!last) k_norm<<<1, 64, 0, stream>>>(Lb);
  }
}

// Round 10
// 787.062 us; speedup vs baseline: 6.6218x; 6.6218x over previous
//
#include <hip/hip_runtime.h>
#include <math.h>

#define TT 36
#define NP 160
#define KDIM 641
#define PP 512
#define KPAD 704          // transposed-x row stride
#define NU 321            // pair-units: u=0 const col; 1..160 cos; 161..320 sin
#define NSLOT 384         // padded unit slots (321..383 stay zero)
#define BT 256            // 4 waves
#define NW 4
#define LAM 0.1f
#define EPSW 0.01f
#define NITER 200
#define NPOW 160

// ---------------- dictionary ----------------
__global__ void k_build_dic(const float* __restrict__ rr, const float* __restrict__ th,
                            float* __restrict__ D, float* __restrict__ outD) {
  int idx = blockIdx.x * blockDim.x + threadIdx.x;
  if (idx >= TT * KDIM) return;
  int t = idx / KDIM, k = idx % KDIM;
  float v;
  if (k == 0) {
    v = 1.0f;
  } else {
    int g = (k - 1) / NP;     // 0:p*cos 1:m*cos 2:p*sin 3:m*sin
    int p = (k - 1) % NP;
    float ft = (float)t;
    float pw = powf(rr[p], ft);
    if ((g == 1 || g == 3) && (t & 1)) pw = -pw;
    float ang = ft * th[p];
    v = pw * ((g < 2) ? cosf(ang) : sinf(ang));
  }
  D[idx] = v;
  outD[idx] = v;
}

// ---------------- G = D D^T (36x36) ----------------
__global__ void k_G(const float* __restrict__ D, float* __restrict__ G) {
  int idx = blockIdx.x * blockDim.x + threadIdx.x;
  if (idx >= TT * TT) return;
  int i = idx / TT, j = idx % TT;
  float s = 0.0f;
  for (int k = 0; k < KDIM; ++k) s = fmaf(D[i * KDIM + k], D[j * KDIM + k], s);
  G[idx] = s;
}

// ---------------- power iteration on 36x36 (one wave): L = ||DtD||_2; mu table ----------------
__global__ void k_power(const float* __restrict__ G, float* __restrict__ Lb,
                        float* __restrict__ mug) {
  int lane = threadIdx.x;   // blockDim = 64
  float g[TT];
#pragma unroll
  for (int j = 0; j < TT; ++j) g[j] = (lane < TT) ? G[lane * TT + j] : 0.0f;
  float v = (lane < TT) ? 1.0f : 0.0f;
  for (int it = 0; it < NPOW; ++it) {
    float u = 0.0f;
#pragma unroll
    for (int j = 0; j < TT; ++j) u = fmaf(g[j], __shfl(v, j, 64), u);
    float s = u * u;
#pragma unroll
    for (int o = 32; o >= 1; o >>= 1) s += __shfl_xor(s, o, 64);
    v = u * rsqrtf(s);
  }
  float u = 0.0f;
#pragma unroll
  for (int j = 0; j < TT; ++j) u = fmaf(g[j], __shfl(v, j, 64), u);
  float num = v * u, den = v * v;
#pragma unroll
  for (int o = 32; o >= 1; o >>= 1) {
    num += __shfl_xor(num, o, 64);
    den += __shfl_xor(den, o, 64);
  }
  if (lane == 0) {
    float L = num / den;   // Rayleigh quotient = lambda_max
    Lb[0] = L;
    Lb[1] = 1.0f / L;
    Lb[3] = 0.0f;          // reset norm accumulator (graph-replay safe)
    float t = 1.0f;
    for (int i = 0; i < NITER; ++i) {
      float tn = 0.5f * (1.0f + sqrtf(1.0f + 4.0f * t * t));
      mug[i] = (t - 1.0f) / tn;
      t = tn;
    }
  }
}

// ---- DPP wave-64 sum; total valid in lane 63 ----
template <int C>
__device__ __forceinline__ float dppadd(float v) {
  int t = __builtin_amdgcn_update_dpp(0, __float_as_int(v), C, 0xf, 0xf, true);
  return v + __int_as_float(t);
}
__device__ __forceinline__ float wave_sum63(float v) {
  v = dppadd<0xB1>(v);    // quad_perm [1,0,3,2]
  v = dppadd<0x4E>(v);    // quad_perm [2,3,0,1]
  v = dppadd<0x141>(v);   // row_half_mirror
  v = dppadd<0x140>(v);   // row_mirror
  v = dppadd<0x142>(v);   // row_bcast15
  v = dppadd<0x143>(v);   // row_bcast31
  return v;               // lane 63 holds the total
}

// plus-group column index of pair-unit u (u < NU)
__device__ __forceinline__ int colmap(int u) {
  return (u == 0) ? 0 : ((u < 161) ? u : u + 160);
}

// ---------------- persistent per-round FISTA: one column per block, 4 waves ----------------
__global__ __launch_bounds__(BT, 1) void k_round(
    const float* __restrict__ Dg, const float* __restrict__ X,
    float* __restrict__ Lb, const float* __restrict__ mug,
    const float* __restrict__ xprev, float* __restrict__ xout,
    int first, int last) {
  __shared__ __align__(16) float2 ylds2[NSLOT];   // slot u = (yP_u, yM_u); 321..383 stay (0,0)
  __shared__ float pbuf[NW * NSLOT];              // per-wave phase-2 partials
  __shared__ float muLDS[NITER];
  __shared__ float rn[NW];

  const int tid  = threadIdx.x;
  const int lane = tid & 63;
  const int w    = tid >> 6;          // wave 0..3; rows t = w + 4i, i<9 (parity = w&1)
  const float sgn = (w & 1) ? -1.0f : 1.0f;
  const int p    = blockIdx.x;        // column

  const float Linv = Lb[1];
  const float sqL  = sqrtf(Linv);
  const float lamL = LAM * Linv;

  // ---- unit ownership: u1 = tid (always < 256 < NU: active), u2 = tid+256 (tid < 65)
  const int u1 = tid;
  const int u2 = tid + 256;
  const bool act2 = (u2 < NU);
  const int kP1 = colmap(u1);
  const int kM1 = (u1 == 0) ? 0 : kP1 + 160;
  const int kP2 = colmap(act2 ? u2 : 0);
  const int kM2 = act2 ? kP2 + 160 : 0;

  // ---- Dq[i][j] = sqrt(Linv) * D[w+4i][colmap(lane+64j)]; zero for pad units
  float Dq[9][6];
#pragma unroll
  for (int i = 0; i < 9; ++i)
#pragma unroll
    for (int j = 0; j < 6; ++j) {
      const int ua = lane + 64 * j;
      Dq[i][j] = (ua < NU) ? Dg[(w + 4 * i) * KDIM + colmap(ua)] * sqL : 0.0f;
    }

  // ---- c0 = Linv*(D^T x_col) via even/odd split (one-time global reads)
  float cmP1, cpP1, cmM1, cpM1, cmP2, cpP2, cmM2, cpM2;
  {
    float sE1 = 0.f, sO1 = 0.f, sE2 = 0.f, sO2 = 0.f;
#pragma unroll 6
    for (int t = 0; t < TT; ++t) {
      const float xv = X[t * PP + p];             // block-uniform
      const float d1 = Dg[t * KDIM + kP1];
      const float d2 = act2 ? Dg[t * KDIM + kP2] : 0.0f;
      if (t & 1) { sO1 = fmaf(d1, xv, sO1); sO2 = fmaf(d2, xv, sO2); }
      else       { sE1 = fmaf(d1, xv, sE1); sE2 = fmaf(d2, xv, sE2); }
    }
    const float c0P1 = (sE1 + sO1) * Linv, c0M1 = (sE1 - sO1) * Linv;
    const float c0P2 = (sE2 + sO2) * Linv, c0M2 = (sE2 - sO2) * Linv;
    float wlP1 = lamL, wlM1 = lamL, wlP2 = lamL, wlM2 = lamL;
    if (!first) {
      const float nl = lamL * Lb[2];              // lam*Linv/||wr||
      wlP1 = nl / (fabsf(xprev[p * KPAD + kP1]) + EPSW);
      wlM1 = nl / (fabsf(xprev[p * KPAD + ((u1 > 0) ? kM1 : kP1)]) + EPSW);
      if (act2) {
        wlP2 = nl / (fabsf(xprev[p * KPAD + kP2]) + EPSW);
        wlM2 = nl / (fabsf(xprev[p * KPAD + kM2]) + EPSW);
      }
    }
    cmP1 = c0P1 - wlP1; cpP1 = c0P1 + wlP1;
    cmM1 = c0M1 - wlM1; cpM1 = c0M1 + wlM1;
    cmP2 = c0P2 - wlP2; cpP2 = c0P2 + wlP2;
    cmM2 = c0M2 - wlM2; cpM2 = c0M2 + wlM2;
  }

  // ---- init LDS
  if (tid < NSLOT) ylds2[tid] = make_float2(0.f, 0.f);
  ylds2[tid + 128] = make_float2(0.f, 0.f);       // covers 256..383 (tid>=128)
  if (tid < NITER) muLDS[tid] = mug[tid];

  float xP1 = 0.f, xM1 = 0.f, yP1 = 0.f, yM1 = 0.f;
  float xP2 = 0.f, xM2 = 0.f, yP2 = 0.f, yM2 = 0.f;

  __syncthreads();

  for (int it = 0; it < NITER; ++it) {
    // ===== phase 1: z rows t=w+4i: acc = sum_units Dq * (yP ± yM) =====
    float acc[9] = {0.f,0.f,0.f,0.f,0.f,0.f,0.f,0.f,0.f};
#pragma unroll
    for (int j = 0; j < 6; ++j) {
      const float2 yv = ylds2[lane + 64 * j];     // ds_read_b64, conflict-free
      const float op = fmaf(sgn, yv.y, yv.x);     // yP ± yM, parity wave-uniform
#pragma unroll
      for (int i = 0; i < 9; ++i) acc[i] = fmaf(Dq[i][j], op, acc[i]);
    }
    // reduce each row; broadcast via SGPR
    float z[9];
#pragma unroll
    for (int i = 0; i < 9; ++i) {
      const float r = wave_sum63(acc[i]);
      z[i] = __int_as_float(__builtin_amdgcn_readlane(__float_as_int(r), 63));
    }
    // ===== phase-2 partials: pw[u] = sum_i Dq[i][u]*z[i] (this wave's rows only) =====
#pragma unroll
    for (int j = 0; j < 6; ++j) {
      float pw = Dq[0][j] * z[0];
#pragma unroll
      for (int i = 1; i < 9; ++i) pw = fmaf(Dq[i][j], z[i], pw);
      pbuf[w * NSLOT + lane + 64 * j] = pw;       // disjoint per wave: no contention
    }
    __syncthreads();

    // ===== owners: sum partials by parity, reconstruct pair rows, shrink, momentum =====
    const float mu = muLDS[it];
    {
      const float sE = pbuf[0 * NSLOT + u1] + pbuf[2 * NSLOT + u1];
      const float sO = pbuf[1 * NSLOT + u1] + pbuf[3 * NSLOT + u1];
      const float sP = sE + sO, sM = sE - sO;     // = Linv*(DtD y) rows kP1,kM1
      float uu, xn;
      uu = yP1 - sP; xn = fmaxf(0.f, uu + cmP1) + fminf(0.f, uu + cpP1);
      yP1 = fmaf(mu, xn - xP1, xn); xP1 = xn;
      uu = yM1 - sM; xn = fmaxf(0.f, uu + cmM1) + fminf(0.f, uu + cpM1);
      yM1 = fmaf(mu, xn - xM1, xn); xM1 = xn;
      ylds2[u1] = make_float2(yP1, (u1 > 0) ? yM1 : 0.0f);
    }
    if (act2) {
      const float sE = pbuf[0 * NSLOT + u2] + pbuf[2 * NSLOT + u2];
      const float sO = pbuf[1 * NSLOT + u2] + pbuf[3 * NSLOT + u2];
      const float sP = sE + sO, sM = sE - sO;
      float uu, xn;
      uu = yP2 - sP; xn = fmaxf(0.f, uu + cmP2) + fminf(0.f, uu + cpP2);
      yP2 = fmaf(mu, xn - xP2, xn); xP2 = xn;
      uu = yM2 - sM; xn = fmaxf(0.f, uu + cmM2) + fminf(0.f, uu + cpM2);
      yM2 = fmaf(mu, xn - xM2, xn); xM2 = xn;
      ylds2[u2] = make_float2(yP2, yM2);
    }
    __syncthreads();
  }

  // ---- emit x
  if (last) {
    xout[kP1 * PP + p] = xP1;
    if (u1 > 0) xout[kM1 * PP + p] = xM1;
    if (act2) { xout[kP2 * PP + p] = xP2; xout[kM2 * PP + p] = xM2; }
  } else {
    xout[p * KPAD + kP1] = xP1;                   // transposed for next round
    if (u1 > 0) xout[p * KPAD + kM1] = xM1;
    if (act2) { xout[p * KPAD + kP2] = xP2; xout[p * KPAD + kM2] = xM2; }
  }

  // ---- fused reweight-norm accumulation: sum of wr^2 over this column
  if (!last) {
    float s;
    {
      const float rP = 1.0f / (fabsf(xP1) + EPSW);
      s = rP * rP;
      if (u1 > 0) { const float rM = 1.0f / (fabsf(xM1) + EPSW); s += rM * rM; }
      if (act2) {
        const float ra = 1.0f / (fabsf(xP2) + EPSW);
        const float rb = 1.0f / (fabsf(xM2) + EPSW);
        s += ra * ra + rb * rb;
      }
    }
    s = wave_sum63(s);
    if (lane == 63) rn[w] = s;
    __syncthreads();
    if (tid == 0) {
      atomicAdd(&Lb[3], rn[0] + rn[1] + rn[2] + rn[3]);   // global atomic: fine
    }
  }
}

// ---------------- finalize norm: Lb[2] = 1/||wr||, reset accumulator ----------------
__global__ void k_norm(float* __restrict__ Lb) {
  if (threadIdx.x == 0) {
    Lb[2] = 1.0f / sqrtf(Lb[3]);
    Lb[3] = 0.0f;
  }
}

// ---------------- host ----------------
extern "C" void kernel_launch(void* const* d_in, const int* in_sizes, int n_in,
                              void* d_out, int out_size, void* d_ws, size_t ws_size,
                              hipStream_t stream) {
  const float* x  = (const float*)d_in[0];
  const float* rr = (const float*)d_in[1];
  const float* th = (const float*)d_in[2];
  float* out = (float*)d_out;
  float* ws  = (float*)d_ws;

  size_t off = 0;
  auto alloc = [&](size_t n) {
    float* p = ws + off;
    off += (n + 63) & ~(size_t)63;
    return p;
  };
  float* D    = alloc((size_t)TT * KDIM);
  float* G    = alloc(TT * TT);
  float* Lb   = alloc(16);
  float* mug  = alloc(NITER);
  float* xa   = alloc((size_t)PP * KPAD);   // transposed intermediate x
  if (off * sizeof(float) > ws_size) return;

  k_build_dic<<<(TT * KDIM + 255) / 256, 256, 0, stream>>>(rr, th, D, out + (size_t)KDIM * PP);
  k_G<<<(TT * TT + 255) / 256, 256, 0, stream>>>(D, G);
  k_power<<<1, 64, 0, stream>>>(G, Lb, mug);

  for (int r = 0; r < 3; ++r) {
    const int first = (r == 0), last = (r == 2);
    float* xo = last ? out : xa;
    k_round<<<PP, BT, 0, stream>>>(D, x, Lb, mug, xa, xo, first, last);
    if (!last) k_norm<<<1, 64, 0, stream>>>(Lb);
  }
}

// Round 11
// 748.336 us; speedup vs baseline: 6.9644x; 1.0517x over previous
//
#include <hip/hip_runtime.h>
#include <math.h>

#define TT 36
#define NP 160
#define KDIM 641
#define PP 512
#define KPAD 704          // transposed-x row stride
#define NU 321            // pair-units: u=0 const col; 1..160 cos; 161..320 sin
#define NSLOT 384         // padded unit slots (321..383 stay zero)
#define BT 512            // 8 waves
#define NW 8
#define LAM 0.1f
#define EPSW 0.01f
#define NITER 200
#define NPOW 160

// ---------------- dictionary ----------------
__global__ void k_build_dic(const float* __restrict__ rr, const float* __restrict__ th,
                            float* __restrict__ D, float* __restrict__ outD) {
  int idx = blockIdx.x * blockDim.x + threadIdx.x;
  if (idx >= TT * KDIM) return;
  int t = idx / KDIM, k = idx % KDIM;
  float v;
  if (k == 0) {
    v = 1.0f;
  } else {
    int g = (k - 1) / NP;     // 0:p*cos 1:m*cos 2:p*sin 3:m*sin
    int p = (k - 1) % NP;
    float ft = (float)t;
    float pw = powf(rr[p], ft);
    if ((g == 1 || g == 3) && (t & 1)) pw = -pw;
    float ang = ft * th[p];
    v = pw * ((g < 2) ? cosf(ang) : sinf(ang));
  }
  D[idx] = v;
  outD[idx] = v;
}

// ---------------- G = D D^T (36x36) ----------------
__global__ void k_G(const float* __restrict__ D, float* __restrict__ G) {
  int idx = blockIdx.x * blockDim.x + threadIdx.x;
  if (idx >= TT * TT) return;
  int i = idx / TT, j = idx % TT;
  float s = 0.0f;
  for (int k = 0; k < KDIM; ++k) s = fmaf(D[i * KDIM + k], D[j * KDIM + k], s);
  G[idx] = s;
}

// ---------------- power iteration on 36x36 (one wave): L = ||DtD||_2; mu table ----------------
__global__ void k_power(const float* __restrict__ G, float* __restrict__ Lb,
                        float* __restrict__ mug) {
  int lane = threadIdx.x;   // blockDim = 64
  float g[TT];
#pragma unroll
  for (int j = 0; j < TT; ++j) g[j] = (lane < TT) ? G[lane * TT + j] : 0.0f;
  float v = (lane < TT) ? 1.0f : 0.0f;
  for (int it = 0; it < NPOW; ++it) {
    float u = 0.0f;
#pragma unroll
    for (int j = 0; j < TT; ++j) u = fmaf(g[j], __shfl(v, j, 64), u);
    float s = u * u;
#pragma unroll
    for (int o = 32; o >= 1; o >>= 1) s += __shfl_xor(s, o, 64);
    v = u * rsqrtf(s);
  }
  float u = 0.0f;
#pragma unroll
  for (int j = 0; j < TT; ++j) u = fmaf(g[j], __shfl(v, j, 64), u);
  float num = v * u, den = v * v;
#pragma unroll
  for (int o = 32; o >= 1; o >>= 1) {
    num += __shfl_xor(num, o, 64);
    den += __shfl_xor(den, o, 64);
  }
  if (lane == 0) {
    float L = num / den;   // Rayleigh quotient = lambda_max
    Lb[0] = L;
    Lb[1] = 1.0f / L;
    Lb[3] = 0.0f;          // reset norm accumulator (graph-replay safe)
    float t = 1.0f;
    for (int i = 0; i < NITER; ++i) {
      float tn = 0.5f * (1.0f + sqrtf(1.0f + 4.0f * t * t));
      mug[i] = (t - 1.0f) / tn;
      t = tn;
    }
  }
}

// ---- DPP wave-64 sum; total valid in lane 63 ----
template <int C>
__device__ __forceinline__ float dppadd(float v) {
  int t = __builtin_amdgcn_update_dpp(0, __float_as_int(v), C, 0xf, 0xf, true);
  return v + __int_as_float(t);
}
__device__ __forceinline__ float wave_sum63(float v) {
  v = dppadd<0xB1>(v);    // quad_perm [1,0,3,2]
  v = dppadd<0x4E>(v);    // quad_perm [2,3,0,1]
  v = dppadd<0x141>(v);   // row_half_mirror
  v = dppadd<0x140>(v);   // row_mirror
  v = dppadd<0x142>(v);   // row_bcast15
  v = dppadd<0x143>(v);   // row_bcast31
  return v;               // lane 63 holds the total
}

// plus-group column index of pair-unit u (u < NU)
__device__ __forceinline__ int colmap(int u) {
  return (u == 0) ? 0 : ((u < 161) ? u : u + 160);
}

// ---------------- persistent per-round FISTA: one column per block, 8 waves ----------------
__global__ __launch_bounds__(BT, 1) void k_round(
    const float* __restrict__ Dg, const float* __restrict__ X,
    float* __restrict__ Lb, const float* __restrict__ mug,
    const float* __restrict__ xprev, float* __restrict__ xout,
    int first, int last) {
  __shared__ __align__(16) float2 ylds2[NSLOT];   // slot u = (yP_u, yM_u); 321..383 stay (0,0)
  __shared__ float pbuf[NW * NSLOT];              // per-wave phase-2 partials (disjoint)
  __shared__ float muLDS[NITER];
  __shared__ float rn[NW];

  const int tid  = threadIdx.x;
  const int lane = tid & 63;
  const int w    = tid >> 6;          // wave 0..7; rows t = w + 8i (parity = w&1)
  const float sgn = (w & 1) ? -1.0f : 1.0f;
  const int p    = blockIdx.x;        // column

  const float Linv = Lb[1];
  const float sqL  = sqrtf(Linv);
  const float lamL = LAM * Linv;

  // ---- unit ownership: one per thread, tid < NU
  const bool act = (tid < NU);
  const int u    = act ? tid : 0;
  const int kP   = colmap(u);
  const int kM   = (u == 0) ? 0 : kP + 160;

  // ---- Dq[i][j] = sqrt(Linv) * D[w+8i][colmap(lane+64j)]; zero for pad units / pad rows
  float Dq[5][6];
#pragma unroll
  for (int i = 0; i < 5; ++i)
#pragma unroll
    for (int j = 0; j < 6; ++j) {
      const int t = w + 8 * i;
      const int ua = lane + 64 * j;
      Dq[i][j] = (t < TT && ua < NU) ? Dg[t * KDIM + colmap(ua)] * sqL : 0.0f;
    }

  // ---- c0 = Linv*(D^T x_col) via even/odd split (one-time global reads)
  float cmP, cpP, cmM, cpM;
  {
    float sE0 = 0.f, sO0 = 0.f;
#pragma unroll 6
    for (int t = 0; t < TT; ++t) {
      const float dv = act ? Dg[t * KDIM + kP] : 0.0f;
      const float xv = X[t * PP + p];             // block-uniform
      if (t & 1) sO0 = fmaf(dv, xv, sO0);
      else       sE0 = fmaf(dv, xv, sE0);
    }
    const float c0P = (sE0 + sO0) * Linv, c0M = (sE0 - sO0) * Linv;
    float wlP = lamL, wlM = lamL;
    if (!first) {
      const float nl = lamL * Lb[2];              // lam*Linv/||wr||
      wlP = nl / (fabsf(xprev[p * KPAD + kP]) + EPSW);
      wlM = nl / (fabsf(xprev[p * KPAD + ((u > 0) ? kM : kP)]) + EPSW);
    }
    cmP = c0P - wlP; cpP = c0P + wlP;
    cmM = c0M - wlM; cpM = c0M + wlM;
  }

  // ---- init LDS
  if (tid < NSLOT) ylds2[tid] = make_float2(0.f, 0.f);
  if (tid < NITER) muLDS[tid] = mug[tid];

  float xP = 0.f, xM = 0.f, yP = 0.f, yM = 0.f;

  __syncthreads();

  for (int it = 0; it < NITER; ++it) {
    // ===== phase 1: z rows t=w+8i: acc = sum_units Dq * (yP ± yM) =====
    float acc[5] = {0.f, 0.f, 0.f, 0.f, 0.f};
#pragma unroll
    for (int j = 0; j < 6; ++j) {
      const float2 yv = ylds2[lane + 64 * j];     // ds_read_b64, conflict-free
      const float op = fmaf(sgn, yv.y, yv.x);     // yP ± yM, parity wave-uniform
#pragma unroll
      for (int i = 0; i < 5; ++i) acc[i] = fmaf(Dq[i][j], op, acc[i]);
    }
    // reduce each row; broadcast via SGPR
    float z[5];
#pragma unroll
    for (int i = 0; i < 5; ++i) {
      const float r = wave_sum63(acc[i]);
      z[i] = __int_as_float(__builtin_amdgcn_readlane(__float_as_int(r), 63));
    }
    // ===== phase-2 partials: pw[u] = sum_i Dq[i][u]*z[i] (this wave's rows only) =====
#pragma unroll
    for (int j = 0; j < 6; ++j) {
      float pw = Dq[0][j] * z[0];
#pragma unroll
      for (int i = 1; i < 5; ++i) pw = fmaf(Dq[i][j], z[i], pw);
      pbuf[w * NSLOT + lane + 64 * j] = pw;       // disjoint per wave: no contention
    }
    __syncthreads();

    // ===== owner: sum partials by parity, reconstruct pair rows, shrink, momentum =====
    const float mu = muLDS[it];
    if (act) {
      const float sE = (pbuf[0 * NSLOT + u] + pbuf[2 * NSLOT + u])
                     + (pbuf[4 * NSLOT + u] + pbuf[6 * NSLOT + u]);
      const float sO = (pbuf[1 * NSLOT + u] + pbuf[3 * NSLOT + u])
                     + (pbuf[5 * NSLOT + u] + pbuf[7 * NSLOT + u]);
      const float sP = sE + sO, sM = sE - sO;     // = Linv*(DtD y) rows kP,kM
      float uu, xn;
      uu = yP - sP; xn = fmaxf(0.f, uu + cmP) + fminf(0.f, uu + cpP);
      yP = fmaf(mu, xn - xP, xn); xP = xn;
      uu = yM - sM; xn = fmaxf(0.f, uu + cmM) + fminf(0.f, uu + cpM);
      yM = fmaf(mu, xn - xM, xn); xM = xn;
      ylds2[u] = make_float2(yP, (u > 0) ? yM : 0.0f);
    }
    __syncthreads();
  }

  // ---- emit x
  if (act) {
    if (last) {
      xout[kP * PP + p] = xP;
      if (u > 0) xout[kM * PP + p] = xM;
    } else {
      xout[p * KPAD + kP] = xP;                   // transposed for next round
      if (u > 0) xout[p * KPAD + kM] = xM;
    }
  }

  // ---- fused reweight-norm accumulation: sum of wr^2 over this column
  if (!last) {
    float s = 0.0f;
    if (act) {
      const float rP = 1.0f / (fabsf(xP) + EPSW);
      s = rP * rP;
      if (u > 0) { const float rM = 1.0f / (fabsf(xM) + EPSW); s += rM * rM; }
    }
    s = wave_sum63(s);
    if (lane == 63) rn[w] = s;
    __syncthreads();
    if (tid == 0) {
      float tot = 0.f;
#pragma unroll
      for (int i = 0; i < NW; ++i) tot += rn[i];
      atomicAdd(&Lb[3], tot);                     // global atomic: fine
    }
  }
}

// ---------------- finalize norm: Lb[2] = 1/||wr||, reset accumulator ----------------
__global__ void k_norm(float* __restrict__ Lb) {
  if (threadIdx.x == 0) {
    Lb[2] = 1.0f / sqrtf(Lb[3]);
    Lb[3] = 0.0f;
  }
}

// ---------------- host ----------------
extern "C" void kernel_launch(void* const* d_in, const int* in_sizes, int n_in,
                              void* d_out, int out_size, void* d_ws, size_t ws_size,
                              hipStream_t stream) {
  const float* x  = (const float*)d_in[0];
  const float* rr = (const float*)d_in[1];
  const float* th = (const float*)d_in[2];
  float* out = (float*)d_out;
  float* ws  = (float*)d_ws;

  size_t off = 0;
  auto alloc = [&](size_t n) {
    float* p = ws + off;
    off += (n + 63) & ~(size_t)63;
    return p;
  };
  float* D    = alloc((size_t)TT * KDIM);
  float* G    = alloc(TT * TT);
  float* Lb   = alloc(16);
  float* mug  = alloc(NITER);
  float* xa   = alloc((size_t)PP * KPAD);   // transposed intermediate x
  if (off * sizeof(float) > ws_size) return;

  k_build_dic<<<(TT * KDIM + 255) / 256, 256, 0, stream>>>(rr, th, D, out + (size_t)KDIM * PP);
  k_G<<<(TT * TT + 255) / 256, 256, 0, stream>>>(D, G);
  k_power<<<1, 64, 0, stream>>>(G, Lb, mug);

  for (int r = 0; r < 3; ++r) {
    const int first = (r == 0), last = (r == 2);
    float* xo = last ? out : xa;
    k_round<<<PP, BT, 0, stream>>>(D, x, Lb, mug, xa, xo, first, last);
    if (!last) k_norm<<<1, 64, 0, stream>>>(Lb);
  }
}